// Round 9
// baseline (208.364 us; speedup 1.0000x reference)
//
#include <hip/hip_runtime.h>
#include <cfloat>
#include <climits>

#define B_   16
#define C_   256
#define K_   1024
#define HW_  4096
#define N_   (B_ * HW_)          // 65536 rows
#define CHW_ (C_ * HW_)          // 1048576

// d_out layout (floats): zq [0, 16777216), seq, losses
#define SEQ_OFF  16777216
#define LOSS_OFF (SEQ_OFF + N_)
// staging inside the zq region (dead after rescue; gather overwrites all):
#define WT_F    0          // w_t f32 [C][K]          (262144 floats)
#define WN_F    262144     // wnorm f32 [K]
#define WNU_F   263168     // WNu int [K]  (wn in u-units)
#define WQ_F    264192     // i8 frag-ordered w hi/lo (524288 B = 131072 floats)
#define RLIST_F 395264     // int [131072]
#define RCNT_F  526336     // int
#define WMAX_F  526337     // float (abs-max of w, via atomicMax on bits)

#define RL_CAP  131072
#define EPS_GAP 0.1f       // f32 distance-gap threshold for rescue
#define XSCL    20.0f      // x fixed hi scale
#define XINV    0.05f
#define XOVF    6.3f       // |x| overflow -> forced exact rescue

typedef int i32x4  __attribute__((ext_vector_type(4)));
typedef int i32x16 __attribute__((ext_vector_type(16)));

__device__ __forceinline__ int pack4b(int b0, int b1, int b2, int b3) {
    return (b0 & 0xFF) | ((b1 & 0xFF) << 8) | ((b2 & 0xFF) << 16) | ((b3 & 0xFF) << 24);
}

// ---------------- prep 0: global abs-max of w ----------------
__global__ __launch_bounds__(256) void wmax_kernel(
    const float* __restrict__ w, unsigned* __restrict__ wmax_bits)
{
    const int tid = blockIdx.x * 256 + threadIdx.x;     // 64 blocks -> 16384 threads
    float mx = 0.f;
#pragma unroll
    for (int q = 0; q < 4; ++q) {
        const float4 v = reinterpret_cast<const float4*>(w)[tid * 4 + q];
        mx = fmaxf(mx, fmaxf(fmaxf(fabsf(v.x), fabsf(v.y)), fmaxf(fabsf(v.z), fabsf(v.w))));
    }
#pragma unroll
    for (int m = 1; m < 64; m <<= 1) mx = fmaxf(mx, __shfl_xor(mx, m, 64));
    if ((threadIdx.x & 63) == 0) atomicMax(wmax_bits, __float_as_uint(mx));
}

// ---------------- prep 1: w -> {i8 hi/lo frag-ordered, w_t f32, wn, WNu} ----------------
// Frag layout (proven r4/r6): chunk(k>>5) 16KB block = [hi 8K | lo 8K];
// elem (k, c): off = chunk*16384 + (c>>5)*1024 + ((c>>4)&1)*512 + (k&31)*16 + (c&15)
__global__ __launch_bounds__(256) void wprep_kernel(
    const float* __restrict__ w, const unsigned* __restrict__ wmax_bits,
    unsigned char* __restrict__ wq, float* __restrict__ w_t,
    float* __restrict__ wn, int* __restrict__ wnu)
{
    const int t = threadIdx.x;
    const int l = t & 63;
    const int k = blockIdx.x * 4 + (t >> 6);   // one wave per code
    const float wmx = __uint_as_float(*wmax_bits);
    const float s   = 127.4f / wmx;            // global hi scale
    const float d1  = wmx / 127.4f;
    const float sl  = s * 256.0f;

    const float4 v4 = *reinterpret_cast<const float4*>(w + (size_t)k * C_ + l * 4);
    float vv[4] = {v4.x, v4.y, v4.z, v4.w};
    float s2 = vv[0]*vv[0] + vv[1]*vv[1] + vv[2]*vv[2] + vv[3]*vv[3];
#pragma unroll
    for (int m = 1; m < 64; m <<= 1) s2 += __shfl_xor(s2, m, 64);

    const int chunk = k >> 5;
    const int col   = k & 31;
#pragma unroll
    for (int q = 0; q < 4; ++q) {
        const int c = l * 4 + q;
        const float v = vv[q];
        const int qh = (int)rintf(v * s);                     // |.| <= 127
        const float r = fmaf((float)qh, -d1, v);
        int ql = (int)rintf(r * sl);
        ql = max(-127, min(127, ql));
        const size_t off = (size_t)chunk * 16384 + (size_t)(c >> 5) * 1024
                         + (size_t)((c >> 4) & 1) * 512 + (size_t)col * 16 + (size_t)(c & 15);
        wq[off]        = (unsigned char)(qh & 0xFF);
        wq[off + 8192] = (unsigned char)(ql & 0xFF);
        w_t[(size_t)c * K_ + k] = v;                          // f32 transpose for rescue
    }
    if (l == 0) {
        wn[k] = s2;
        wnu[k] = (int)rintf(s2 * (2560.0f / d1));             // wn / u, u = d1/2560
    }
}

// ---------------- pass A: i8 MFMA argmin, 4 independent accumulator streams ----------------
// 512 blocks x 256 threads (4 waves). Block: 128 rows. Wave wv: rows wv*32..+31.
// KEY CHANGE vs r8: accumulator chains broken 16-deep -> {4,4,8,8}-deep across
// aH1/aH2 (ks parity) and aX1 (ah*bl) / aX2 (al*bh). Exact int math unchanged.
// LDS 36KB (xs aliases wbuf[0]; chunk0 prefetch -> wbuf[1]) for 2-block residency.
__global__ __launch_bounds__(256) void argmin_i8_kernel(
    const float* __restrict__ x, const unsigned char* __restrict__ wq,
    const int* __restrict__ wnu, const unsigned* __restrict__ wmax_bits,
    float* __restrict__ seq, int* __restrict__ rlist, int* __restrict__ rcount)
{
    __shared__ __align__(16) int wbuf[2][4096];   // 2 x 16KB B double-buffer
    __shared__ int wnu_s[1024];

    const int t  = threadIdx.x;
    const int l  = t & 63;
    const int wv = t >> 6;
    const int col = l & 31;
    const int khalf = l >> 5;
    const int nb = blockIdx.x;
    const int b  = nb >> 5;
    const int hw0 = (nb & 31) << 7;
    const float* xb = x + (size_t)b * CHW_ + hw0;

#define STAGE32(ch, bufidx)                                                       \
    {                                                                             \
        _Pragma("unroll")                                                         \
        for (int rr = 0; rr < 4; ++rr) {                                          \
            const int sIdx = wv * 4 + rr;                                         \
            __builtin_amdgcn_global_load_lds(                                     \
                (const __attribute__((address_space(1))) void*)                   \
                    (wq + (size_t)(ch) * 16384 + sIdx * 1024 + l * 16),           \
                (__attribute__((address_space(3))) void*)                         \
                    (&wbuf[bufidx][sIdx * 256]), 16, 0, 0);                       \
        }                                                                         \
    }

    STAGE32(0, 1);                       // prefetch chunk 0 into buf1 (xs uses buf0)

    // wnu -> LDS
#pragma unroll
    for (int i = 0; i < 4; ++i) wnu_s[t + i * 256] = wnu[t + i * 256];

    // ---- x staging + two-level i8 quantization into A-fragments (r6-validated) ----
    i32x4 ah8[8], al8[8];
    float mx = 0.f;
    {
        float* xs = reinterpret_cast<float*>(&wbuf[0][0]);   // [32 ch][128 rows] = 16KB
        const int row = wv * 32 + col;
#pragma unroll
        for (int cc = 0; cc < 8; ++cc) {
#pragma unroll
            for (int qq = 0; qq < 4; ++qq) {      // 1024 float4 slots
                const int fi = qq * 256 + t;
                const int cl = fi >> 5;           // 0..31
                const int r4 = (fi & 31) << 2;    // 0..124
                const float4 v = *reinterpret_cast<const float4*>(
                    xb + (size_t)(cc * 32 + cl) * HW_ + r4);
                *reinterpret_cast<float4*>(&xs[cl * 128 + r4]) = v;
            }
            __syncthreads();
            int qh[16], ql[16];
#pragma unroll
            for (int j = 0; j < 16; ++j) {
                const float v = xs[(khalf * 16 + j) * 128 + row];
                mx = fmaxf(mx, fabsf(v));
                int h = (int)rintf(v * XSCL);
                h = max(-127, min(127, h));
                const float r = fmaf((float)h, -XINV, v);
                int lo = (int)rintf(r * (XSCL * 256.0f));
                lo = max(-127, min(127, lo));
                qh[j] = h; ql[j] = lo;
            }
            ah8[cc] = (i32x4){ pack4b(qh[0],qh[1],qh[2],qh[3]),   pack4b(qh[4],qh[5],qh[6],qh[7]),
                               pack4b(qh[8],qh[9],qh[10],qh[11]), pack4b(qh[12],qh[13],qh[14],qh[15]) };
            al8[cc] = (i32x4){ pack4b(ql[0],ql[1],ql[2],ql[3]),   pack4b(ql[4],ql[5],ql[6],ql[7]),
                               pack4b(ql[8],ql[9],ql[10],ql[11]), pack4b(ql[12],ql[13],ql[14],ql[15]) };
            __syncthreads();
        }
    }

    // overflow rows -> forced exact rescue
    mx = fmaxf(mx, __shfl_xor(mx, 32, 64));
    if (khalf == 0 && mx > XOVF) {
        const int pos = atomicAdd(rcount, 1);
        if (pos < RL_CAP) rlist[pos] = b * HW_ + hw0 + wv * 32 + col;
    }

    const float wmx = __uint_as_float(*wmax_bits);
    const int eps_u = (int)(32614.4f / wmx);   // EPS_GAP * 2560 * 127.4 / wmax

    int m1p[16], m2p[16];
#pragma unroll
    for (int r = 0; r < 16; ++r) { m1p[r] = INT_MAX; m2p[r] = INT_MAX; }

#pragma unroll 1
    for (int ch = 0; ch < 32; ++ch) {
        const int cur = 1 ^ (ch & 1);            // ch0 -> buf1 (prefetched during setup)
        if (ch < 31) STAGE32(ch + 1, cur ^ 1);
        const int wnu_l = wnu_s[ch * 32 + col];

        // 4 independent accumulator streams (chains: 4,4,8,8 instead of 8,16)
        i32x16 aH1, aH2, aX1, aX2;
#pragma unroll
        for (int r = 0; r < 16; ++r) { aH1[r] = 0; aH2[r] = 0; aX1[r] = 0; aX2[r] = 0; }

#pragma unroll
        for (int ks = 0; ks < 8; ks += 2) {
            const i32x4 bh0 = *reinterpret_cast<const i32x4*>(&wbuf[cur][ks * 256 + (l << 2)]);
            const i32x4 bl0 = *reinterpret_cast<const i32x4*>(&wbuf[cur][2048 + ks * 256 + (l << 2)]);
            const i32x4 bh1 = *reinterpret_cast<const i32x4*>(&wbuf[cur][(ks + 1) * 256 + (l << 2)]);
            const i32x4 bl1 = *reinterpret_cast<const i32x4*>(&wbuf[cur][2048 + (ks + 1) * 256 + (l << 2)]);
            aH1 = __builtin_amdgcn_mfma_i32_32x32x32_i8(ah8[ks],     bh0, aH1, 0, 0, 0);
            aH2 = __builtin_amdgcn_mfma_i32_32x32x32_i8(ah8[ks + 1], bh1, aH2, 0, 0, 0);
            aX1 = __builtin_amdgcn_mfma_i32_32x32x32_i8(ah8[ks],     bl0, aX1, 0, 0, 0);
            aX2 = __builtin_amdgcn_mfma_i32_32x32x32_i8(al8[ks],     bh0, aX2, 0, 0, 0);
            aX1 = __builtin_amdgcn_mfma_i32_32x32x32_i8(ah8[ks + 1], bl1, aX1, 0, 0, 0);
            aX2 = __builtin_amdgcn_mfma_i32_32x32x32_i8(al8[ks + 1], bh1, aX2, 0, 0, 0);
        }

        // D = WNu - (aH*256 + aX); pack chunk id in 5 LSBs; min1/min2 update
#pragma unroll
        for (int r = 0; r < 16; ++r) {
            const int T  = ((aH1[r] + aH2[r]) << 8) + aX1[r] + aX2[r];
            const int D  = wnu_l - T;
            const int Dp = (D & ~31) | ch;
            m2p[r] = min(m2p[r], max(m1p[r], Dp));
            m1p[r] = min(m1p[r], Dp);
        }
        __syncthreads();
    }
#undef STAGE32

    // rebuild k, then merge across the 32 code-lanes (lane bits 0..4)
    int k1[16];
#pragma unroll
    for (int r = 0; r < 16; ++r) k1[r] = ((m1p[r] & 31) << 5) | col;
#pragma unroll
    for (int mask = 1; mask <= 16; mask <<= 1) {
#pragma unroll
        for (int r = 0; r < 16; ++r) {
            const int om1 = __shfl_xor(m1p[r], mask, 64);
            const int ok1 = __shfl_xor(k1[r],  mask, 64);
            const int om2 = __shfl_xor(m2p[r], mask, 64);
            const int nm2 = min(min(m2p[r], om2), max(m1p[r], om1));
            const bool lt = om1 < m1p[r] || (om1 == m1p[r] && ok1 < k1[r]);
            m1p[r] = lt ? om1 : m1p[r];
            k1[r]  = lt ? ok1 : k1[r];
            m2p[r] = nm2;
        }
    }

    if (col == 0) {
#pragma unroll
        for (int r = 0; r < 16; ++r) {
            const int row_local = (r & 3) + 8 * (r >> 2) + 4 * khalf;   // 0..31
            const int n = b * HW_ + hw0 + wv * 32 + row_local;
            seq[n] = (float)k1[r];
            if (m2p[r] - m1p[r] < eps_u) {
                const int pos = atomicAdd(rcount, 1);
                if (pos < RL_CAP) rlist[pos] = n;
            }
        }
    }
}

// ---------------- rescue: exact f32 re-argmin for flagged rows ----------------
__global__ __launch_bounds__(256) void rescue_kernel(
    const float* __restrict__ x, const float* __restrict__ w_t,
    const float* __restrict__ wnorm, const int* __restrict__ rlist,
    const int* __restrict__ rcount, float* __restrict__ seq)
{
    __shared__ float xr[C_];
    __shared__ float bvs[4];
    __shared__ int   bis[4];
    const int t = threadIdx.x;
    const int cnt = min(*rcount, RL_CAP);
    for (int ii = blockIdx.x; ii < cnt; ii += gridDim.x) {
        const int n = rlist[ii];
        const int b = n >> 12, hw = n & 4095;
        xr[t] = x[(size_t)b * CHW_ + (size_t)t * HW_ + hw];
        __syncthreads();
        float best = FLT_MAX; int bidx = 0;
#pragma unroll
        for (int q = 0; q < 4; ++q) {
            const int k = t + q * 256;
            float acc = 0.f;
            for (int c = 0; c < C_; ++c) acc = fmaf(xr[c], w_t[(size_t)c * K_ + k], acc);
            const float d = wnorm[k] - 2.f * acc;
            if (d < best || (d == best && k < bidx)) { best = d; bidx = k; }
        }
#pragma unroll
        for (int mask = 1; mask < 64; mask <<= 1) {
            const float ov = __shfl_xor(best, mask, 64);
            const int   oi = __shfl_xor(bidx, mask, 64);
            if (ov < best || (ov == best && oi < bidx)) { best = ov; bidx = oi; }
        }
        if ((t & 63) == 0) { bvs[t >> 6] = best; bis[t >> 6] = bidx; }
        __syncthreads();
        if (t == 0) {
            float bv = bvs[0]; int bi = bis[0];
#pragma unroll
            for (int w2 = 1; w2 < 4; ++w2)
                if (bvs[w2] < bv || (bvs[w2] == bv && bis[w2] < bi)) { bv = bvs[w2]; bi = bis[w2]; }
            seq[n] = (float)bi;
        }
        __syncthreads();
    }
}

// ---------------- gather z (via LDS-staged w rows), write zq, accumulate loss ----------------
__global__ __launch_bounds__(256) void gather_kernel(
    const float* __restrict__ x, const float* __restrict__ w,
    const float* __restrict__ seqf, float* __restrict__ zq,
    double* __restrict__ loss_acc)
{
    __shared__ float ws[C_ * 64];      // [c][row] transposed, 64KB
    const int t   = threadIdx.x;
    const int nb  = blockIdx.x;
    const int b   = nb >> 6;
    const int hw0 = (nb & 63) << 6;
    {
        const int j = t >> 2, q = t & 3;
        const int idx = (int)seqf[b * HW_ + hw0 + j];
        const float* wrow = w + (size_t)idx * C_ + q * 64;
#pragma unroll
        for (int m = 0; m < 16; ++m) {
            const float4 v = *reinterpret_cast<const float4*>(wrow + m * 4);
            const int c = q * 64 + m * 4;
            ws[(c + 0) * 64 + j] = v.x;
            ws[(c + 1) * 64 + j] = v.y;
            ws[(c + 2) * 64 + j] = v.z;
            ws[(c + 3) * 64 + j] = v.w;
        }
    }
    __syncthreads();
    const int r  = t & 63;
    const int cg = t >> 6;
    const float* xb = x  + (size_t)b * CHW_ + hw0;
    float*       zb = zq + (size_t)b * CHW_ + hw0;
    float lsum = 0.f;
#pragma unroll 4
    for (int cc = 0; cc < 64; ++cc) {
        const int c = cg * 64 + cc;
        const float xv = xb[(size_t)c * HW_ + r];
        const float d  = ws[c * 64 + r] - xv;
        zb[(size_t)c * HW_ + r] = xv + d;
        lsum += d * d;
    }
#pragma unroll
    for (int off = 32; off >= 1; off >>= 1) lsum += __shfl_down(lsum, off, 64);
    __syncthreads();
    if ((t & 63) == 0) ws[t >> 6] = lsum;
    __syncthreads();
    if (t == 0)
        atomicAdd(loss_acc, (double)(ws[0] + ws[1] + ws[2] + ws[3]));
}

__global__ void finalize_kernel(const double* __restrict__ acc, float* __restrict__ loss_out)
{
    const double s = *acc;
    const float m = (float)(s / (double)((size_t)N_ * C_));
    loss_out[0] = m;
    loss_out[1] = m;
}

extern "C" void kernel_launch(void* const* d_in, const int* in_sizes, int n_in,
                              void* d_out, int out_size, void* d_ws, size_t ws_size,
                              hipStream_t stream)
{
    (void)in_sizes; (void)n_in; (void)out_size; (void)d_ws; (void)ws_size;
    const float* x = (const float*)d_in[0];
    const float* w = (const float*)d_in[1];
    float* out = (float*)d_out;

    float*         w_t    = out + WT_F;
    float*         wn     = out + WN_F;
    int*           wnu    = (int*)(out + WNU_F);
    unsigned char* wq     = (unsigned char*)(out + WQ_F);
    int*           rlist  = (int*)(out + RLIST_F);
    int*           rcount = (int*)(out + RCNT_F);
    unsigned*      wmaxb  = (unsigned*)(out + WMAX_F);
    float*         seq    = out + SEQ_OFF;
    double*        loss_acc = (double*)(out + LOSS_OFF);

    hipMemsetAsync((void*)wmaxb, 0, 4, stream);
    hipMemsetAsync((void*)rcount, 0, 4, stream);
    wmax_kernel<<<64, 256, 0, stream>>>(w, wmaxb);
    wprep_kernel<<<256, 256, 0, stream>>>(w, wmaxb, wq, w_t, wn, wnu);
    argmin_i8_kernel<<<512, 256, 0, stream>>>(x, wq, wnu, wmaxb, seq, rlist, rcount);
    rescue_kernel<<<1024, 256, 0, stream>>>(x, w_t, wn, rlist, rcount, seq);
    hipMemsetAsync((char*)d_out + (size_t)LOSS_OFF * 4, 0, 8, stream);
    gather_kernel<<<1024, 256, 0, stream>>>(x, w, seq, out, loss_acc);
    finalize_kernel<<<1, 1, 0, stream>>>(loss_acc, out + LOSS_OFF);
}

// Round 10
// 193.210 us; speedup vs baseline: 1.0784x; 1.0784x over previous
//
#include <hip/hip_runtime.h>
#include <cfloat>
#include <climits>

#define B_   16
#define C_   256
#define K_   1024
#define HW_  4096
#define N_   (B_ * HW_)          // 65536 rows
#define CHW_ (C_ * HW_)          // 1048576

// d_out layout (floats): zq [0, 16777216), seq, losses
#define SEQ_OFF  16777216
#define LOSS_OFF (SEQ_OFF + N_)
// staging inside the zq region (dead after rescue; gather overwrites all):
#define WT_F    0          // w_t f32 [C][K]          (262144 floats)
#define WN_F    262144     // wnorm f32 [K]
#define WNU_F   263168     // WNu int [K]  (wn in u-units)
#define WQ_F    264192     // i8 frag-ordered w hi/lo (524288 B = 131072 floats)
#define RLIST_F 395264     // int [131072]
#define RCNT_F  526336     // int
#define WMAX_F  526337     // float (abs-max of w, via atomicMax on bits)

#define RL_CAP  131072
#define EPS_GAP 0.1f       // f32 distance-gap threshold for rescue
#define XSCL    20.0f      // x fixed hi scale
#define XINV    0.05f
#define XOVF    6.3f       // |x| overflow -> forced exact rescue

typedef int i32x4  __attribute__((ext_vector_type(4)));
typedef int i32x16 __attribute__((ext_vector_type(16)));

__device__ __forceinline__ int pack4b(int b0, int b1, int b2, int b3) {
    return (b0 & 0xFF) | ((b1 & 0xFF) << 8) | ((b2 & 0xFF) << 16) | ((b3 & 0xFF) << 24);
}

// ---------------- prep 0: global abs-max of w ----------------
__global__ __launch_bounds__(256) void wmax_kernel(
    const float* __restrict__ w, unsigned* __restrict__ wmax_bits)
{
    const int tid = blockIdx.x * 256 + threadIdx.x;     // 64 blocks -> 16384 threads
    float mx = 0.f;
#pragma unroll
    for (int q = 0; q < 4; ++q) {
        const float4 v = reinterpret_cast<const float4*>(w)[tid * 4 + q];
        mx = fmaxf(mx, fmaxf(fmaxf(fabsf(v.x), fabsf(v.y)), fmaxf(fabsf(v.z), fabsf(v.w))));
    }
#pragma unroll
    for (int m = 1; m < 64; m <<= 1) mx = fmaxf(mx, __shfl_xor(mx, m, 64));
    if ((threadIdx.x & 63) == 0) atomicMax(wmax_bits, __float_as_uint(mx));
}

// ---------------- prep 1: w -> {i8 hi/lo frag-ordered, w_t f32, wn, WNu} ----------------
// Frag layout (proven r4/r6): chunk(k>>5) 16KB block = [hi 8K | lo 8K];
// elem (k, c): off = chunk*16384 + (c>>5)*1024 + ((c>>4)&1)*512 + (k&31)*16 + (c&15)
__global__ __launch_bounds__(256) void wprep_kernel(
    const float* __restrict__ w, const unsigned* __restrict__ wmax_bits,
    unsigned char* __restrict__ wq, float* __restrict__ w_t,
    float* __restrict__ wn, int* __restrict__ wnu)
{
    const int t = threadIdx.x;
    const int l = t & 63;
    const int k = blockIdx.x * 4 + (t >> 6);   // one wave per code
    const float wmx = __uint_as_float(*wmax_bits);
    const float s   = 127.4f / wmx;            // global hi scale
    const float d1  = wmx / 127.4f;
    const float sl  = s * 256.0f;

    const float4 v4 = *reinterpret_cast<const float4*>(w + (size_t)k * C_ + l * 4);
    float vv[4] = {v4.x, v4.y, v4.z, v4.w};
    float s2 = vv[0]*vv[0] + vv[1]*vv[1] + vv[2]*vv[2] + vv[3]*vv[3];
#pragma unroll
    for (int m = 1; m < 64; m <<= 1) s2 += __shfl_xor(s2, m, 64);

    const int chunk = k >> 5;
    const int col   = k & 31;
#pragma unroll
    for (int q = 0; q < 4; ++q) {
        const int c = l * 4 + q;
        const float v = vv[q];
        const int qh = (int)rintf(v * s);                     // |.| <= 127
        const float r = fmaf((float)qh, -d1, v);
        int ql = (int)rintf(r * sl);
        ql = max(-127, min(127, ql));
        const size_t off = (size_t)chunk * 16384 + (size_t)(c >> 5) * 1024
                         + (size_t)((c >> 4) & 1) * 512 + (size_t)col * 16 + (size_t)(c & 15);
        wq[off]        = (unsigned char)(qh & 0xFF);
        wq[off + 8192] = (unsigned char)(ql & 0xFF);
        w_t[(size_t)c * K_ + k] = v;                          // f32 transpose for rescue
    }
    if (l == 0) {
        wn[k] = s2;
        wnu[k] = (int)rintf(s2 * (2560.0f / d1));             // wn / u, u = d1/2560
    }
}

// ---------------- pass A: i8 MFMA argmin — barrier-free 1-wave blocks ----------------
// 2048 blocks x 64 threads. One wave owns 32 rows (one b, hw0..hw0+31).
// NO LDS, NO barriers: x loaded per-lane direct to regs (lane = row);
// B fragments loaded per-chunk direct from frag-ordered wq (L2-resident)
// via global_load_dwordx4 at lane*16. Math/epilogue identical to r6 (validated).
__global__ __launch_bounds__(64, 2) void argmin_i8_kernel(
    const float* __restrict__ x, const unsigned char* __restrict__ wq,
    const int* __restrict__ wnu, const unsigned* __restrict__ wmax_bits,
    float* __restrict__ seq, int* __restrict__ rlist, int* __restrict__ rcount)
{
    const int l = threadIdx.x;           // 0..63
    const int col = l & 31;              // row of x (A), code-col of D
    const int khalf = l >> 5;
    const int nb = blockIdx.x;           // 0..2047
    const int b  = nb >> 7;
    const int hw0 = (nb & 127) << 5;
    const float* xb = x + (size_t)b * CHW_ + hw0 + col;

    // ---- x direct load + two-level i8 quantization into A fragments ----
    i32x4 ah8[8], al8[8];
    float mx = 0.f;
#pragma unroll
    for (int cc = 0; cc < 8; ++cc) {
        int qh[16], ql[16];
#pragma unroll
        for (int j = 0; j < 16; ++j) {
            const float v = xb[(size_t)(cc * 32 + khalf * 16 + j) * HW_];
            mx = fmaxf(mx, fabsf(v));
            int h = (int)rintf(v * XSCL);
            h = max(-127, min(127, h));
            const float r = fmaf((float)h, -XINV, v);
            int lo = (int)rintf(r * (XSCL * 256.0f));
            lo = max(-127, min(127, lo));
            qh[j] = h; ql[j] = lo;
        }
        ah8[cc] = (i32x4){ pack4b(qh[0],qh[1],qh[2],qh[3]),   pack4b(qh[4],qh[5],qh[6],qh[7]),
                           pack4b(qh[8],qh[9],qh[10],qh[11]), pack4b(qh[12],qh[13],qh[14],qh[15]) };
        al8[cc] = (i32x4){ pack4b(ql[0],ql[1],ql[2],ql[3]),   pack4b(ql[4],ql[5],ql[6],ql[7]),
                           pack4b(ql[8],ql[9],ql[10],ql[11]), pack4b(ql[12],ql[13],ql[14],ql[15]) };
    }

    // overflow rows -> forced exact rescue (lane covers half the channels of its row)
    mx = fmaxf(mx, __shfl_xor(mx, 32, 64));
    if (khalf == 0 && mx > XOVF) {
        const int pos = atomicAdd(rcount, 1);
        if (pos < RL_CAP) rlist[pos] = b * HW_ + hw0 + col;
    }

    const float wmx = __uint_as_float(*wmax_bits);
    const int eps_u = (int)(32614.4f / wmx);   // EPS_GAP * 2560 * 127.4 / wmax

    int m1p[16], m2p[16];
#pragma unroll
    for (int r = 0; r < 16; ++r) { m1p[r] = INT_MAX; m2p[r] = INT_MAX; }

#pragma unroll 1
    for (int ch = 0; ch < 32; ++ch) {
        const unsigned char* base = wq + (size_t)ch * 16384 + l * 16;
        const int wnu_l = wnu[ch * 32 + col];

        i32x16 aH, aX;
#pragma unroll
        for (int r = 0; r < 16; ++r) { aH[r] = 0; aX[r] = 0; }

#pragma unroll
        for (int half = 0; half < 2; ++half) {
            // batch 8 independent L2 loads (4 hi + 4 lo fragments)
            i32x4 bh[4], bl[4];
#pragma unroll
            for (int q = 0; q < 4; ++q) {
                const int ks = half * 4 + q;
                bh[q] = *reinterpret_cast<const i32x4*>(base + ks * 1024);
                bl[q] = *reinterpret_cast<const i32x4*>(base + 8192 + ks * 1024);
            }
#pragma unroll
            for (int q = 0; q < 4; ++q) {
                const int ks = half * 4 + q;
                aH = __builtin_amdgcn_mfma_i32_32x32x32_i8(ah8[ks], bh[q], aH, 0, 0, 0);
                aX = __builtin_amdgcn_mfma_i32_32x32x32_i8(ah8[ks], bl[q], aX, 0, 0, 0);
                aX = __builtin_amdgcn_mfma_i32_32x32x32_i8(al8[ks], bh[q], aX, 0, 0, 0);
            }
        }

        // D = WNu - (aH*256 + aX); pack chunk id in 5 LSBs; min1/min2 update
#pragma unroll
        for (int r = 0; r < 16; ++r) {
            const int T  = (aH[r] << 8) + aX[r];
            const int D  = wnu_l - T;
            const int Dp = (D & ~31) | ch;
            m2p[r] = min(m2p[r], max(m1p[r], Dp));
            m1p[r] = min(m1p[r], Dp);
        }
    }

    // rebuild k, then merge across the 32 code-lanes (lane bits 0..4)
    int k1[16];
#pragma unroll
    for (int r = 0; r < 16; ++r) k1[r] = ((m1p[r] & 31) << 5) | col;
#pragma unroll
    for (int mask = 1; mask <= 16; mask <<= 1) {
#pragma unroll
        for (int r = 0; r < 16; ++r) {
            const int om1 = __shfl_xor(m1p[r], mask, 64);
            const int ok1 = __shfl_xor(k1[r],  mask, 64);
            const int om2 = __shfl_xor(m2p[r], mask, 64);
            const int nm2 = min(min(m2p[r], om2), max(m1p[r], om1));
            const bool lt = om1 < m1p[r] || (om1 == m1p[r] && ok1 < k1[r]);
            m1p[r] = lt ? om1 : m1p[r];
            k1[r]  = lt ? ok1 : k1[r];
            m2p[r] = nm2;
        }
    }

    if (col == 0) {
#pragma unroll
        for (int r = 0; r < 16; ++r) {
            const int row_local = (r & 3) + 8 * (r >> 2) + 4 * khalf;   // 0..31
            const int n = b * HW_ + hw0 + row_local;
            seq[n] = (float)k1[r];
            if (m2p[r] - m1p[r] < eps_u) {
                const int pos = atomicAdd(rcount, 1);
                if (pos < RL_CAP) rlist[pos] = n;
            }
        }
    }
}

// ---------------- rescue: exact f32 re-argmin for flagged rows ----------------
__global__ __launch_bounds__(256) void rescue_kernel(
    const float* __restrict__ x, const float* __restrict__ w_t,
    const float* __restrict__ wnorm, const int* __restrict__ rlist,
    const int* __restrict__ rcount, float* __restrict__ seq)
{
    __shared__ float xr[C_];
    __shared__ float bvs[4];
    __shared__ int   bis[4];
    const int t = threadIdx.x;
    const int cnt = min(*rcount, RL_CAP);
    for (int ii = blockIdx.x; ii < cnt; ii += gridDim.x) {
        const int n = rlist[ii];
        const int b = n >> 12, hw = n & 4095;
        xr[t] = x[(size_t)b * CHW_ + (size_t)t * HW_ + hw];
        __syncthreads();
        float best = FLT_MAX; int bidx = 0;
#pragma unroll
        for (int q = 0; q < 4; ++q) {
            const int k = t + q * 256;
            float acc = 0.f;
            for (int c = 0; c < C_; ++c) acc = fmaf(xr[c], w_t[(size_t)c * K_ + k], acc);
            const float d = wnorm[k] - 2.f * acc;
            if (d < best || (d == best && k < bidx)) { best = d; bidx = k; }
        }
#pragma unroll
        for (int mask = 1; mask < 64; mask <<= 1) {
            const float ov = __shfl_xor(best, mask, 64);
            const int   oi = __shfl_xor(bidx, mask, 64);
            if (ov < best || (ov == best && oi < bidx)) { best = ov; bidx = oi; }
        }
        if ((t & 63) == 0) { bvs[t >> 6] = best; bis[t >> 6] = bidx; }
        __syncthreads();
        if (t == 0) {
            float bv = bvs[0]; int bi = bis[0];
#pragma unroll
            for (int w2 = 1; w2 < 4; ++w2)
                if (bvs[w2] < bv || (bvs[w2] == bv && bis[w2] < bi)) { bv = bvs[w2]; bi = bis[w2]; }
            seq[n] = (float)bi;
        }
        __syncthreads();
    }
}

// ---------------- gather z (via LDS-staged w rows), write zq, accumulate loss ----------------
__global__ __launch_bounds__(256) void gather_kernel(
    const float* __restrict__ x, const float* __restrict__ w,
    const float* __restrict__ seqf, float* __restrict__ zq,
    double* __restrict__ loss_acc)
{
    __shared__ float ws[C_ * 64];      // [c][row] transposed, 64KB
    const int t   = threadIdx.x;
    const int nb  = blockIdx.x;
    const int b   = nb >> 6;
    const int hw0 = (nb & 63) << 6;
    {
        const int j = t >> 2, q = t & 3;
        const int idx = (int)seqf[b * HW_ + hw0 + j];
        const float* wrow = w + (size_t)idx * C_ + q * 64;
#pragma unroll
        for (int m = 0; m < 16; ++m) {
            const float4 v = *reinterpret_cast<const float4*>(wrow + m * 4);
            const int c = q * 64 + m * 4;
            ws[(c + 0) * 64 + j] = v.x;
            ws[(c + 1) * 64 + j] = v.y;
            ws[(c + 2) * 64 + j] = v.z;
            ws[(c + 3) * 64 + j] = v.w;
        }
    }
    __syncthreads();
    const int r  = t & 63;
    const int cg = t >> 6;
    const float* xb = x  + (size_t)b * CHW_ + hw0;
    float*       zb = zq + (size_t)b * CHW_ + hw0;
    float lsum = 0.f;
#pragma unroll 4
    for (int cc = 0; cc < 64; ++cc) {
        const int c = cg * 64 + cc;
        const float xv = xb[(size_t)c * HW_ + r];
        const float d  = ws[c * 64 + r] - xv;
        zb[(size_t)c * HW_ + r] = xv + d;
        lsum += d * d;
    }
#pragma unroll
    for (int off = 32; off >= 1; off >>= 1) lsum += __shfl_down(lsum, off, 64);
    __syncthreads();
    if ((t & 63) == 0) ws[t >> 6] = lsum;
    __syncthreads();
    if (t == 0)
        atomicAdd(loss_acc, (double)(ws[0] + ws[1] + ws[2] + ws[3]));
}

__global__ void finalize_kernel(const double* __restrict__ acc, float* __restrict__ loss_out)
{
    const double s = *acc;
    const float m = (float)(s / (double)((size_t)N_ * C_));
    loss_out[0] = m;
    loss_out[1] = m;
}

extern "C" void kernel_launch(void* const* d_in, const int* in_sizes, int n_in,
                              void* d_out, int out_size, void* d_ws, size_t ws_size,
                              hipStream_t stream)
{
    (void)in_sizes; (void)n_in; (void)out_size; (void)d_ws; (void)ws_size;
    const float* x = (const float*)d_in[0];
    const float* w = (const float*)d_in[1];
    float* out = (float*)d_out;

    float*         w_t    = out + WT_F;
    float*         wn     = out + WN_F;
    int*           wnu    = (int*)(out + WNU_F);
    unsigned char* wq     = (unsigned char*)(out + WQ_F);
    int*           rlist  = (int*)(out + RLIST_F);
    int*           rcount = (int*)(out + RCNT_F);
    unsigned*      wmaxb  = (unsigned*)(out + WMAX_F);
    float*         seq    = out + SEQ_OFF;
    double*        loss_acc = (double*)(out + LOSS_OFF);

    hipMemsetAsync((void*)wmaxb, 0, 4, stream);
    hipMemsetAsync((void*)rcount, 0, 4, stream);
    wmax_kernel<<<64, 256, 0, stream>>>(w, wmaxb);
    wprep_kernel<<<256, 256, 0, stream>>>(w, wmaxb, wq, w_t, wn, wnu);
    argmin_i8_kernel<<<2048, 64, 0, stream>>>(x, wq, wnu, wmaxb, seq, rlist, rcount);
    rescue_kernel<<<1024, 256, 0, stream>>>(x, w_t, wn, rlist, rcount, seq);
    hipMemsetAsync((char*)d_out + (size_t)LOSS_OFF * 4, 0, 8, stream);
    gather_kernel<<<1024, 256, 0, stream>>>(x, w, seq, out, loss_acc);
    finalize_kernel<<<1, 1, 0, stream>>>(loss_acc, out + LOSS_OFF);
}